// Round 3
// baseline (852.552 us; speedup 1.0000x reference)
//
#include <hip/hip_runtime.h>
#include <stdint.h>

#define NCOLS  24576
#define TPB    512
#define VPT    (NCOLS / (TPB * 4))   // 12 uint4 per thread
#define EPT    (VPT * 4)             // 48 elements per thread
#define KSEL   64
#define NWAVES (TPB / 64)            // 8
#define CAP    1024
#define CAPW   (CAP / NWAVES)        // 128 per-wave candidate segment

typedef uint32_t u32x4 __attribute__((ext_vector_type(4)));

// key transform: b ^ 0x80000000. Monotonic for non-negative floats (the only
// region we rank); negatives land below key(+0)=0x80000000 in scrambled order
// (irrelevant: never in the searched domain; ReLU zeroes them). Involution.

__global__ void __launch_bounds__(TPB, 6)  // cap VGPR ~85: 48 keys + 16 cnd fit, 3 blocks/CU
topk_relu_scatter(const float* __restrict__ x, float* __restrict__ out) {
  const int row  = blockIdx.x;
  const int tid  = threadIdx.x;
  const int lane = tid & 63;
  const int wid  = tid >> 6;

  const uint4* __restrict__ xr =
      reinterpret_cast<const uint4*>(x + (size_t)row * NCOLS);
  u32x4* __restrict__ orow =
      reinterpret_cast<u32x4*>(out + (size_t)row * NCOLS);

  // ---- load row: 12 coalesced uint4 per thread, transform to keys ----
  uint32_t key[EPT];
  #pragma unroll
  for (int i = 0; i < VPT; ++i) {
    uint4 v = xr[tid + TPB * i];
    key[4*i+0] = v.x ^ 0x80000000u;
    key[4*i+1] = v.y ^ 0x80000000u;
    key[4*i+2] = v.z ^ 0x80000000u;
    key[4*i+3] = v.w ^ 0x80000000u;
  }

  __shared__ uint32_t s_candK[CAP];
  __shared__ int      s_candI[CAP];
  __shared__ int      s_wcnt[NWAVES];
  __shared__ int      s_part[NWAVES];
  __shared__ int      s_cnt;
  __shared__ int      s_m;
  __shared__ uint32_t s_k64;
  __shared__ int      s_c, s_e;
  __shared__ int      s_incIdx[KSEL];
  __shared__ int      s_ninc;
  __shared__ int      s_thrIdx;

  // ---- wave-private zero of own segment (no barrier needed) ----
  #pragma unroll
  for (int j = 0; j < CAPW / 64; ++j)
    s_candK[wid * CAPW + j * 64 + lane] = 0u;
  if (tid == 0) { s_m = 0; s_ninc = 0; }

  // ---- atomic-free gather with fixed pivot P0 = key(2.0f) ----
  // E[survivors] = 24576 * P(N(0,1) >= 2) ~= 560; bounds [KSEL, CAP] are >20
  // sigma away, per-wave CAPW=128 is ~7 sigma. Any violation -> exact fallback.
  const uint32_t P0 = 0xC0000000u;
  const uint64_t lanemask = (1ull << lane) - 1ull;
  int wcnt = 0;
  #pragma unroll
  for (int i = 0; i < EPT; ++i) {
    bool p = key[i] >= P0;
    uint64_t mk = __ballot(p);
    if (p) {
      int pos = wcnt + (int)__popcll(mk & lanemask);
      if (pos < CAPW) {
        s_candK[wid * CAPW + pos] = key[i];
        s_candI[wid * CAPW + pos] = 4 * (tid + TPB * (i >> 2)) + (i & 3);
      }
    }
    wcnt += (int)__popcll(mk);
  }
  if (lane == 0) s_wcnt[wid] = wcnt;
  __syncthreads();   // the only barrier on the happy path

  int total = 0, wmax = 0;
  #pragma unroll
  for (int w = 0; w < NWAVES; ++w) {
    int c = s_wcnt[w];
    total += c;
    wmax = c > wmax ? c : wmax;
  }

  if (total >= KSEL && total <= CAP && wmax <= CAPW) {
    // ================= happy path =================
    // All waves redundantly binary-search the zero-padded 1024-slot array in
    // registers (pads=0 < P0 never counted). No further barriers in mode 0.
    uint32_t cnd[16];
    #pragma unroll
    for (int j = 0; j < 16; ++j) cnd[j] = s_candK[lane + 64 * j];  // 2-way alias: free

    uint32_t slo = P0, shi = 0xFFFFFFFFu;   // invariant: count(>=slo) >= KSEL
    while (slo < shi) {
      uint32_t mid = slo + ((shi - slo) >> 1) + 1;
      int cnt = 0;
      #pragma unroll
      for (int j = 0; j < 16; ++j)
        cnt += (int)__popcll(__ballot(cnd[j] >= mid));
      if (cnt >= KSEL) slo = mid; else shi = mid - 1;
    }
    int cge = 0, cgt = 0;
    #pragma unroll
    for (int j = 0; j < 16; ++j) {
      cge += (int)__popcll(__ballot(cnd[j] >= slo));
      cgt += (int)__popcll(__ballot(cnd[j] >  slo));
    }
    const uint32_t K64 = slo;            // uniform across all waves
    const int needed = KSEL - cgt;
    const int e = cge - cgt;

    if (e == needed) {
      // mode 0: include all >= K64. Included => kk >= K64 >= P0 => float >= 2.0,
      // ReLU is identity, stored bits are exactly kk ^ sign.
      #pragma unroll
      for (int i = 0; i < VPT; ++i) {
        u32x4 o;
        #pragma unroll
        for (int j = 0; j < 4; ++j) {
          uint32_t kk = key[4*i+j];
          o[j] = (kk >= K64) ? (kk ^ 0x80000000u) : 0u;
        }
        __builtin_nontemporal_store(o, &orow[tid + TPB * i]);
      }
    } else {
      // tie at K64 (block-uniform, measure-zero for random floats):
      // include lowest-index `needed` equals (lax.top_k order)
      for (int p = tid; p < CAP; p += TPB) {
        if (s_candK[p] == K64) {
          int myi = s_candI[p];
          int rk = 0;
          for (int q = 0; q < CAP; ++q)
            if (s_candK[q] == K64 && s_candI[q] < myi) rk++;
          if (rk < needed) { int t = atomicAdd(&s_ninc, 1); s_incIdx[t] = myi; }
        }
      }
      __syncthreads();
      int ninc = s_ninc;
      #pragma unroll
      for (int i = 0; i < VPT; ++i) {
        u32x4 o;
        #pragma unroll
        for (int j = 0; j < 4; ++j) {
          uint32_t kk = key[4*i+j];
          bool inc = kk > K64;
          if (kk == K64) {
            int col = 4 * (tid + TPB * i) + j;
            for (int t = 0; t < ninc; ++t)
              if (s_incIdx[t] == col) { inc = true; break; }
          }
          o[j] = inc ? (kk ^ 0x80000000u) : 0u;
        }
        __builtin_nontemporal_store(o, &orow[tid + TPB * i]);
      }
    }
    return;
  }

  // ================= generic fallback (any data; R2-verified logic) =================
  {
    auto blockCount = [&](uint32_t thr) -> int {
      int c = 0;
      #pragma unroll
      for (int i = 0; i < EPT; ++i) c += (key[i] >= thr) ? 1 : 0;
      #pragma unroll
      for (int off = 32; off > 0; off >>= 1) c += __shfl_down(c, off, 64);
      if (lane == 0) s_part[wid] = c;
      __syncthreads();
      if (tid == 0) {
        int t = 0;
        for (int w = 0; w < NWAVES; ++w) t += s_part[w];
        s_cnt = t;
      }
      __syncthreads();
      return s_cnt;
    };
    auto blockCountEq = [&](uint32_t eqv, int idxLim) -> int {
      int c = 0;
      #pragma unroll
      for (int i = 0; i < EPT; ++i) {
        int col = 4 * (tid + TPB * (i >> 2)) + (i & 3);
        c += (key[i] == eqv && col < idxLim) ? 1 : 0;
      }
      #pragma unroll
      for (int off = 32; off > 0; off >>= 1) c += __shfl_down(c, off, 64);
      if (lane == 0) s_part[wid] = c;
      __syncthreads();
      if (tid == 0) {
        int t = 0;
        for (int w = 0; w < NWAVES; ++w) t += s_part[w];
        s_cnt = t;
      }
      __syncthreads();
      return s_cnt;
    };

    // coarse binary search until survivors fit in CAP
    uint32_t lo = 0x80000000u, hi = 0xFFFFFFFFu;
    int loCnt = NCOLS;  // sentinel
    while (lo < hi) {
      uint32_t mid = lo + ((hi - lo) >> 1) + 1;
      int cnt = blockCount(mid);
      if (cnt >= KSEL) { lo = mid; loCnt = cnt; }
      else             { hi = mid - 1; }
      if (loCnt <= CAP) break;
    }

    uint32_t K64;
    int mode = 0;  // 0: all >= K64; 1: include-list; 2: col < thrIdx

    if (loCnt <= CAP) {
      // atomic gather (s_m zeroed before first barrier; ordered by blockCount syncs)
      #pragma unroll
      for (int i = 0; i < EPT; ++i) {
        if (key[i] >= lo) {
          int p = atomicAdd(&s_m, 1);
          if (p < CAP) {
            s_candK[p] = key[i];
            s_candI[p] = 4 * (tid + TPB * (i >> 2)) + (i & 3);
          }
        }
      }
      __syncthreads();
      int m = s_m; if (m > CAP) m = CAP;

      if (tid < 64) {   // single-wave masked ballot search
        uint32_t cnd[16];
        #pragma unroll
        for (int j = 0; j < 16; ++j) {
          int idx = lane + 64 * j;
          uint32_t v = s_candK[idx];
          cnd[j] = (idx < m) ? v : 0u;
        }
        uint32_t slo = lo, shi = 0xFFFFFFFFu;
        while (slo < shi) {
          uint32_t mid = slo + ((shi - slo) >> 1) + 1;
          int cnt = 0;
          #pragma unroll
          for (int j = 0; j < 16; ++j)
            cnt += (int)__popcll(__ballot(cnd[j] >= mid));
          if (cnt >= KSEL) slo = mid; else shi = mid - 1;
        }
        int cge = 0, cgt = 0;
        #pragma unroll
        for (int j = 0; j < 16; ++j) {
          cge += (int)__popcll(__ballot(cnd[j] >= slo));
          cgt += (int)__popcll(__ballot(cnd[j] >  slo));
        }
        if (lane == 0) { s_k64 = slo; s_c = cgt; s_e = cge - cgt; }
      }
      __syncthreads();
      K64 = s_k64;
      int c = s_c, e = s_e;
      int needed = KSEL - c;
      if (e > needed) {
        mode = 1;
        for (int p = tid; p < m; p += TPB) {
          if (s_candK[p] == K64) {
            int myi = s_candI[p];
            int rk = 0;
            for (int j = 0; j < m; ++j)
              if (s_candK[j] == K64 && s_candI[j] < myi) rk++;
            if (rk < needed) { int t = atomicAdd(&s_ninc, 1); s_incIdx[t] = myi; }
          }
        }
        __syncthreads();
      }
    } else {
      // collapsed window with massive ties (adversarial only)
      K64 = lo;
      int c = (K64 == 0xFFFFFFFFu) ? 0 : blockCount(K64 + 1);
      #pragma unroll
      for (int i = 0; i < EPT; ++i) {
        if (key[i] == K64) {
          int p = atomicAdd(&s_m, 1);
          if (p < CAP) s_candI[p] = 4 * (tid + TPB * (i >> 2)) + (i & 3);
        }
      }
      __syncthreads();
      int e = s_m;
      int needed = KSEL - c;
      if (needed < 0) needed = 0;
      if (e > needed) {
        if (e <= CAP) {
          mode = 1;
          for (int p = tid; p < e; p += TPB) {
            int myi = s_candI[p];
            int rk = 0;
            for (int j = 0; j < e; ++j) if (s_candI[j] < myi) rk++;
            if (rk < needed) { int t = atomicAdd(&s_ninc, 1); s_incIdx[t] = myi; }
          }
          __syncthreads();
        } else {
          mode = 2;
          int ilo = 0, ihi = NCOLS;
          while (ilo < ihi) {
            int imid = (ilo + ihi) >> 1;
            int cq = blockCountEq(K64, imid);
            if (cq >= needed) ihi = imid; else ilo = imid + 1;
          }
          if (tid == 0) s_thrIdx = ilo;
          __syncthreads();
        }
      }
    }

    // fallback write
    int ninc   = (mode == 1) ? s_ninc   : 0;
    int thrIdx = (mode == 2) ? s_thrIdx : 0;
    #pragma unroll
    for (int i = 0; i < VPT; ++i) {
      u32x4 o;
      #pragma unroll
      for (int j = 0; j < 4; ++j) {
        uint32_t kk = key[4*i+j];
        bool inc = kk > K64;
        if (kk == K64) {
          int col = 4 * (tid + TPB * i) + j;
          if (mode == 0) {
            inc = true;
          } else if (mode == 1) {
            inc = false;
            for (int t = 0; t < ninc; ++t)
              if (s_incIdx[t] == col) { inc = true; break; }
          } else {
            inc = col < thrIdx;
          }
        }
        o[j] = inc ? (kk ^ 0x80000000u) : 0u;
      }
      __builtin_nontemporal_store(o, &orow[tid + TPB * i]);
    }
  }
}

extern "C" void kernel_launch(void* const* d_in, const int* in_sizes, int n_in,
                              void* d_out, int out_size, void* d_ws, size_t ws_size,
                              hipStream_t stream) {
  (void)in_sizes; (void)n_in; (void)d_ws; (void)ws_size;
  const float* x = (const float*)d_in[0];
  float* out = (float*)d_out;
  int nrows = out_size / NCOLS;  // 4096
  topk_relu_scatter<<<nrows, TPB, 0, stream>>>(x, out);
}

// Round 4
// 710.862 us; speedup vs baseline: 1.1993x; 1.1993x over previous
//
#include <hip/hip_runtime.h>
#include <stdint.h>

#define NCOLS  24576
#define TPB    512
#define VPT    (NCOLS / (TPB * 4))   // 12 x 16B chunks per thread
#define KSEL   64
#define NWAVES (TPB / 64)            // 8
#define CAP    1024
#define CAPW   (CAP / NWAVES)        // 128 per-wave candidate segment

typedef uint32_t u32x4 __attribute__((ext_vector_type(4)));

// key transform: b ^ 0x80000000. Monotonic for non-negative floats (the only
// region we rank); negatives land below key(+0) in scrambled order —
// irrelevant (never searched; ReLU zeroes them). Involution restores bits.

__global__ void __launch_bounds__(TPB, 8)   // VGPR cap 64; live set ~30 — no spill
topk_relu_scatter(const float* __restrict__ x, float* __restrict__ out) {
  const int row  = blockIdx.x;
  const int tid  = threadIdx.x;
  const int lane = tid & 63;
  const int wid  = tid >> 6;

  const u32x4* __restrict__ xr =
      reinterpret_cast<const u32x4*>(x + (size_t)row * NCOLS);
  u32x4* __restrict__ orow =
      reinterpret_cast<u32x4*>(out + (size_t)row * NCOLS);
  float* __restrict__ orowf = out + (size_t)row * NCOLS;

  __shared__ __align__(16) uint32_t s_candK[CAP];
  __shared__ int      s_candI[CAP];
  __shared__ int      s_wcnt[NWAVES];
  __shared__ int      s_part[NWAVES];
  __shared__ int      s_cnt;
  __shared__ int      s_m;
  __shared__ uint32_t s_k64;
  __shared__ int      s_c, s_e;
  __shared__ int      s_thrIdx;

  // wave-private zero of own segment (pads stay 0 < P0: never counted/fixed)
  s_candK[wid * CAPW + lane]      = 0u;
  s_candK[wid * CAPW + 64 + lane] = 0u;
  if (tid == 0) s_m = 0;

  // ---- fused pass: load -> ballot-gather -> provisional store ----
  // P0 = key(2.0f). E[survivors/row] = 24576*P(N>=2) ~= 560 (sigma ~23):
  // bounds [64,1024] are >20 sigma, per-wave 128 is ~7 sigma. Violation -> fallback.
  const uint32_t P0 = 0xC0000000u;
  const uint64_t lanemask = (1ull << lane) - 1ull;
  int wcnt = 0;
  #pragma unroll 4
  for (int i = 0; i < VPT; ++i) {
    u32x4 v = xr[tid + TPB * i];
    u32x4 o;
    #pragma unroll
    for (int j = 0; j < 4; ++j) {
      uint32_t kk = v[j] ^ 0x80000000u;
      bool p = kk >= P0;
      uint64_t mk = __ballot(p);
      if (p) {
        int pos = wcnt + (int)__popcll(mk & lanemask);
        if (pos < CAPW) {
          s_candK[wid * CAPW + pos] = kk;
          s_candI[wid * CAPW + pos] = 4 * (tid + TPB * i) + j;
        }
      }
      wcnt += (int)__popcll(mk);
      o[j] = p ? v[j] : 0u;   // f >= 2.0 here: ReLU identity, exact bits
    }
    orow[tid + TPB * i] = o;  // normal store: line stays in this XCD's L2
  }
  if (lane == 0) s_wcnt[wid] = wcnt;
  __syncthreads();            // also drains stores (same-L2 ordering for fixup)

  int total = 0, wmax = 0;
  #pragma unroll
  for (int w = 0; w < NWAVES; ++w) {
    int c = s_wcnt[w];
    total += c;
    wmax = c > wmax ? c : wmax;
  }

  if (total >= KSEL && total <= CAP && wmax <= CAPW) {
    // ---------- happy path: redundant ballot binary search + sparse fixup ----------
    u32x4 cnd[4];
    #pragma unroll
    for (int q = 0; q < 4; ++q)   // any lane<->slot permutation is fine: we only count
      cnd[q] = reinterpret_cast<const u32x4*>(s_candK)[lane + 64 * q];

    uint32_t slo = P0, shi = 0xFFFFFFFFu;   // invariant: count(>=slo) >= KSEL
    while (slo < shi) {
      uint32_t mid = slo + ((shi - slo) >> 1) + 1;   // in (slo, shi]
      int cnt = 0;
      #pragma unroll
      for (int q = 0; q < 4; ++q)
        #pragma unroll
        for (int j = 0; j < 4; ++j)
          cnt += (int)__popcll(__ballot(cnd[q][j] >= mid));
      if (cnt >= KSEL) slo = mid; else shi = mid - 1;
    }
    int cge = 0, cgt = 0;
    #pragma unroll
    for (int q = 0; q < 4; ++q) {
      #pragma unroll
      for (int j = 0; j < 4; ++j) {
        cge += (int)__popcll(__ballot(cnd[q][j] >= slo));
        cgt += (int)__popcll(__ballot(cnd[q][j] >  slo));
      }
    }
    const uint32_t K64 = slo;          // identical in every wave
    const int e = cge - cgt;
    const int needed = KSEL - cgt;

    if (e == needed) {
      // no tie ambiguity: zero every candidate strictly below K64
      for (int p = tid; p < CAP; p += TPB) {
        uint32_t k = s_candK[p];
        if (k >= P0 && k < K64) orowf[s_candI[p]] = 0.0f;
      }
    } else {
      // tie at K64 (measure-zero for random floats): keep lowest-index `needed`
      for (int p = tid; p < CAP; p += TPB) {
        uint32_t k = s_candK[p];
        if (k >= P0) {
          bool zero = (k < K64);
          if (k == K64) {
            int myi = s_candI[p];
            int rk = 0;
            for (int q = 0; q < CAP; ++q)
              if (s_candK[q] == K64 && s_candI[q] < myi) rk++;
            zero = (rk >= needed);
          }
          if (zero) orowf[s_candI[p]] = 0.0f;
        }
      }
    }
    return;
  }

  // ================= generic fallback (any data; streams from global) =================
  {
    auto blockCountGE = [&](uint32_t thr) -> int {
      int c = 0;
      for (int i = 0; i < VPT; ++i) {
        u32x4 v = xr[tid + TPB * i];   // L2/L3-hot re-read
        #pragma unroll
        for (int j = 0; j < 4; ++j) c += ((v[j] ^ 0x80000000u) >= thr) ? 1 : 0;
      }
      #pragma unroll
      for (int off = 32; off > 0; off >>= 1) c += __shfl_down(c, off, 64);
      if (lane == 0) s_part[wid] = c;
      __syncthreads();
      if (tid == 0) {
        int t = 0;
        for (int w = 0; w < NWAVES; ++w) t += s_part[w];
        s_cnt = t;
      }
      __syncthreads();
      return s_cnt;
    };
    auto blockCountEq = [&](uint32_t eqv, int idxLim) -> int {
      int c = 0;
      for (int i = 0; i < VPT; ++i) {
        u32x4 v = xr[tid + TPB * i];
        #pragma unroll
        for (int j = 0; j < 4; ++j) {
          int col = 4 * (tid + TPB * i) + j;
          c += ((v[j] ^ 0x80000000u) == eqv && col < idxLim) ? 1 : 0;
        }
      }
      #pragma unroll
      for (int off = 32; off > 0; off >>= 1) c += __shfl_down(c, off, 64);
      if (lane == 0) s_part[wid] = c;
      __syncthreads();
      if (tid == 0) {
        int t = 0;
        for (int w = 0; w < NWAVES; ++w) t += s_part[w];
        s_cnt = t;
      }
      __syncthreads();
      return s_cnt;
    };

    // coarse binary search until survivors fit in CAP
    uint32_t lo = 0x80000000u, hi = 0xFFFFFFFFu;
    int loCnt = NCOLS;  // sentinel
    while (lo < hi) {
      uint32_t mid = lo + ((hi - lo) >> 1) + 1;
      int cnt = blockCountGE(mid);
      if (cnt >= KSEL) { lo = mid; loCnt = cnt; }
      else             { hi = mid - 1; }
      if (loCnt <= CAP) break;
    }

    uint32_t K64;
    int mode = 0;       // 0: all >= K64; 1: rank-limited equals; 2: col < thrIdx
    int needed = 0;

    if (loCnt <= CAP) {
      // gather survivors (atomic; s_m zeroed pre-first-barrier)
      for (int i = 0; i < VPT; ++i) {
        u32x4 v = xr[tid + TPB * i];
        #pragma unroll
        for (int j = 0; j < 4; ++j) {
          uint32_t kk = v[j] ^ 0x80000000u;
          if (kk >= lo) {
            int p = atomicAdd(&s_m, 1);
            if (p < CAP) {
              s_candK[p] = kk;
              s_candI[p] = 4 * (tid + TPB * i) + j;
            }
          }
        }
      }
      __syncthreads();
      int m = s_m; if (m > CAP) m = CAP;

      if (tid < 64) {   // single-wave masked ballot search
        uint32_t cnd[16];
        #pragma unroll
        for (int j = 0; j < 16; ++j) {
          int idx = lane + 64 * j;
          uint32_t v = s_candK[idx];
          cnd[j] = (idx < m) ? v : 0u;
        }
        uint32_t slo = lo, shi = 0xFFFFFFFFu;
        while (slo < shi) {
          uint32_t mid = slo + ((shi - slo) >> 1) + 1;
          int cnt = 0;
          #pragma unroll
          for (int j = 0; j < 16; ++j)
            cnt += (int)__popcll(__ballot(cnd[j] >= mid));
          if (cnt >= KSEL) slo = mid; else shi = mid - 1;
        }
        int cge = 0, cgt = 0;
        #pragma unroll
        for (int j = 0; j < 16; ++j) {
          cge += (int)__popcll(__ballot(cnd[j] >= slo));
          cgt += (int)__popcll(__ballot(cnd[j] >  slo));
        }
        if (lane == 0) { s_k64 = slo; s_c = cgt; s_e = cge - cgt; }
      }
      __syncthreads();
      K64 = s_k64;
      needed = KSEL - s_c;
      if (s_e > needed) mode = 1;   // rank-limited equals, using s_candK/I (m entries)
    } else {
      // collapsed window with massive ties (adversarial only)
      K64 = lo;
      int c = (K64 == 0xFFFFFFFFu) ? 0 : blockCountGE(K64 + 1);
      needed = KSEL - c;
      if (needed < 0) needed = 0;
      int e = blockCountEq(K64, NCOLS);
      if (e > needed) {
        mode = 2;
        int ilo = 0, ihi = NCOLS;
        while (ilo < ihi) {
          int imid = (ilo + ihi) >> 1;
          int cq = blockCountEq(K64, imid);
          if (cq >= needed) ihi = imid; else ilo = imid + 1;
        }
        if (tid == 0) s_thrIdx = ilo;
        __syncthreads();
      }
    }

    // full-row rewrite (overwrites provisional data)
    int m = s_m; if (m > CAP) m = CAP;
    int thrIdx = (mode == 2) ? s_thrIdx : 0;
    for (int i = 0; i < VPT; ++i) {
      u32x4 v = xr[tid + TPB * i];
      u32x4 o;
      #pragma unroll
      for (int j = 0; j < 4; ++j) {
        uint32_t kk = v[j] ^ 0x80000000u;
        bool inc = kk > K64;
        if (kk == K64) {
          int col = 4 * (tid + TPB * i) + j;
          if (mode == 0) {
            inc = true;
          } else if (mode == 1) {
            int rk = 0;
            for (int q = 0; q < m; ++q)
              if (s_candK[q] == K64 && s_candI[q] < col) rk++;
            inc = (rk < needed);
          } else {
            inc = col < thrIdx;
          }
        }
        // included => kk >= K64 >= 0x80000000 => float >= +0: ReLU identity
        o[j] = inc ? (kk ^ 0x80000000u) : 0u;
      }
      orow[tid + TPB * i] = o;
    }
  }
}

extern "C" void kernel_launch(void* const* d_in, const int* in_sizes, int n_in,
                              void* d_out, int out_size, void* d_ws, size_t ws_size,
                              hipStream_t stream) {
  (void)in_sizes; (void)n_in; (void)d_ws; (void)ws_size;
  const float* x = (const float*)d_in[0];
  float* out = (float*)d_out;
  int nrows = out_size / NCOLS;  // 4096
  topk_relu_scatter<<<nrows, TPB, 0, stream>>>(x, out);
}